// Round 10
// baseline (1671.500 us; speedup 1.0000x reference)
//
#include <hip/hip_runtime.h>
#include <stdint.h>
#include <stddef.h>

// ---------------------------------------------------------------------------
// TwoHemiRNNTanh_asymmetric_single_readout  (B=512, T=400, hidden 258)
// R10 = R8 (proven 858us scan) + two surgical fixes:
//  (a) asm VOLATILE W pin -> W really stays in VGPRs (R9's non-volatile pin
//      was duplicated+rematerialized by LLVM; VGPR_Count=64 proved it).
//  (b) gen_uv/gen_c fused into the scan (uvb prologue + per-chunk gen_cbuf),
//      numerics validated in R9. Deletes 2 dispatches + C HBM round-trip.
// Everything else (8-way ks split, PK skew, allred8, lgkm-only barriers,
// zs-in-flush) is unchanged from R8.
// ---------------------------------------------------------------------------

typedef uint32_t u32x4 __attribute__((ext_vector_type(4)));
typedef __fp16   f16x2 __attribute__((ext_vector_type(2)));

#define TF_ROUND(x0, x1, r) { x0 += x1; x1 = ((x1) << (r)) | ((x1) >> (32 - (r))); x1 ^= x0; }

__host__ __device__ inline void tf2x32(uint32_t k0, uint32_t k1, uint32_t x0, uint32_t x1,
                                       uint32_t& o0, uint32_t& o1) {
  uint32_t ks2 = k0 ^ k1 ^ 0x1BD11BDAu;
  x0 += k0; x1 += k1;
  TF_ROUND(x0, x1, 13) TF_ROUND(x0, x1, 15) TF_ROUND(x0, x1, 26) TF_ROUND(x0, x1, 6)
  x0 += k1; x1 += ks2 + 1u;
  TF_ROUND(x0, x1, 17) TF_ROUND(x0, x1, 29) TF_ROUND(x0, x1, 16) TF_ROUND(x0, x1, 24)
  x0 += ks2; x1 += k0 + 2u;
  TF_ROUND(x0, x1, 13) TF_ROUND(x0, x1, 15) TF_ROUND(x0, x1, 26) TF_ROUND(x0, x1, 6)
  x0 += k0; x1 += k1 + 3u;
  TF_ROUND(x0, x1, 17) TF_ROUND(x0, x1, 29) TF_ROUND(x0, x1, 16) TF_ROUND(x0, x1, 24)
  x0 += k1; x1 += ks2 + 4u;
  TF_ROUND(x0, x1, 13) TF_ROUND(x0, x1, 15) TF_ROUND(x0, x1, 26) TF_ROUND(x0, x1, 6)
  x0 += ks2; x1 += k0 + 5u;
  o0 = x0; o1 = x1;
}

__device__ __forceinline__ float jax_erfinv(float x) {
  float w = -log1pf(-x * x);
  float p;
  if (w < 5.0f) {
    w -= 2.5f;
    p = 2.81022636e-08f;
    p = fmaf(p, w, 3.43273939e-07f);
    p = fmaf(p, w, -3.5233877e-06f);
    p = fmaf(p, w, -4.39150654e-06f);
    p = fmaf(p, w, 0.00021858087f);
    p = fmaf(p, w, -0.00125372503f);
    p = fmaf(p, w, -0.00417768164f);
    p = fmaf(p, w, 0.246640727f);
    p = fmaf(p, w, 1.50140941f);
  } else {
    w = sqrtf(w) - 3.0f;
    p = -0.000200214257f;
    p = fmaf(p, w, 0.000100950558f);
    p = fmaf(p, w, 0.00134934322f);
    p = fmaf(p, w, -0.00367342844f);
    p = fmaf(p, w, 0.00573950773f);
    p = fmaf(p, w, -0.0076224613f);
    p = fmaf(p, w, 0.00943887047f);
    p = fmaf(p, w, 1.00167406f);
    p = fmaf(p, w, 2.83297682f);
  }
  return p * x;
}

__device__ __forceinline__ float uni_from_bits(uint32_t bits) {
  float f = __uint_as_float((bits >> 9) | 0x3f800000u) - 1.0f;
  float x = f * 2.0f + (-0.99999994f);
  return fmaxf(-0.99999994f, x);
}

__device__ __forceinline__ float noise_from_bits(uint32_t bits) {
  float n = 1.41421356f * jax_erfinv(uni_from_bits(bits));
  return 0.15811388f * n;   // sqrt(2/A)*SIG = sqrt(10)*0.05
}

__device__ __forceinline__ float my_tanh(float x) {
  float e = __expf(2.0f * x);
  return 1.0f - 2.0f / (e + 1.0f);
}

__device__ __forceinline__ uint32_t packh2(float a, float b) {
  f16x2 h = __builtin_amdgcn_cvt_pkrtz(a, b);
  return __builtin_bit_cast(uint32_t, h);
}

__device__ __forceinline__ void pkfma(uint32_t& acc, uint32_t w, uint32_t h) {
  asm("v_pk_fma_f16 %0, %1, %2, %0" : "+v"(acc) : "v"(w), "v"(h));
}

__device__ __forceinline__ float cvt2f(uint32_t a) {
  f16x2 v = __builtin_bit_cast(f16x2, a);
  return (float)v.x + (float)v.y;
}

// LDS-only barrier (no vmcnt drain)
__device__ __forceinline__ void step_barrier() {
  asm volatile("s_waitcnt lgkmcnt(0)" ::: "memory");
  __builtin_amdgcn_s_barrier();
}

// 8-lane allreduce: xor1,xor2 via DPP quad_perm (VALU); xor4 via ds_swizzle.
__device__ __forceinline__ float allred8(float x) {
  int t = __builtin_amdgcn_update_dpp(0, __float_as_int(x), 0xB1, 0xF, 0xF, true);
  x += __int_as_float(t);
  t = __builtin_amdgcn_update_dpp(0, __float_as_int(x), 0x4E, 0xF, 0xF, true);
  x += __int_as_float(t);
  t = __builtin_amdgcn_ds_swizzle(__float_as_int(x), 0x101F);
  x += __int_as_float(t);
  return x;
}

// packed-slot skew: kp in [0,128) -> 20*(kp>>4) + (kp&15); spans 160 dwords.
#define PK(kp) (20 * ((kp) >> 4) + ((kp) & 15))

// ---------------------------------------------------------------------------
__device__ __forceinline__ float wval(int j, int k,
    const float* w_ll, const float* w_rl, const float* w_lr, const float* w_rr) {
  if (j < 2) return (k < 2) ? w_ll[j * 2 + k] : w_rl[j * 256 + (k - 2)];
  return (k < 2) ? w_lr[(j - 2) * 2 + k] : w_rr[(j - 2) * 256 + (k - 2)];
}

// Wp: packed f16 pairs [258][128]; Wtail: f32 [258][2] (k=256,257).
__global__ __launch_bounds__(256) void build_w_kernel(
    const float* __restrict__ w_ll, const float* __restrict__ w_rl,
    const float* __restrict__ w_lr, const float* __restrict__ w_rr,
    uint32_t* __restrict__ Wp, float* __restrict__ Wtail) {
  int i = blockIdx.x * 256 + threadIdx.x;
  if (i < 258 * 128) {
    int j = i >> 7, kp = i & 127;
    float v0 = wval(j, 2 * kp, w_ll, w_rl, w_lr, w_rr);
    float v1 = wval(j, 2 * kp + 1, w_ll, w_rl, w_lr, w_rr);
    Wp[i] = packh2(v0, v1);
  }
  if (i < 516) {
    int j = i >> 1, k = 256 + (i & 1);
    Wtail[i] = wval(j, k, w_ll, w_rl, w_lr, w_rr);
  }
}

// ---------------------------------------------------------------------------
// K_scan: 512 blocks x 512 thr, 1 batch row/block, 2 blocks/CU.
// Thread (g=tid>>3, ks=tid&7): 4 rows (j0=2+4g) x 32 k, W PINNED in 64 VGPR
// (volatile asm). Dots via asm v_pk_fma_f16, f32 finalize + allred8.
// C generated on the fly per chunk; u,v precomputed in LDS prologue.
// zs computed per 8-step chunk from sbuf. hbp/wlp use PK skew (conflict-free).
// ---------------------------------------------------------------------------
__global__ __launch_bounds__(512, 4) void rnn_scan_kernel(
    const uint32_t* __restrict__ Wp, const float* __restrict__ Wtail,
    float* __restrict__ hsC,
    const float* __restrict__ w_ro, const float* __restrict__ b_ro,
    const float* __restrict__ xs,
    const float* __restrict__ w_xl, const float* __restrict__ w_xr,
    const float* __restrict__ b_ll, const float* __restrict__ b_rr,
    uint32_t k0a, uint32_t k0b, uint32_t k1a, uint32_t k1b,
    uint32_t k2a, uint32_t k2b) {
  __shared__ __align__(16) uint32_t hbp[2][168];
  __shared__ __align__(16) uint32_t wlp[2][168];
  __shared__ __align__(16) float cbuf[8][260];
  __shared__ __align__(16) float sbuf[8][260];
  __shared__ float wrol[260];
  __shared__ float uvb[400][4];     // u0,u1,v0,v1 per t
  __shared__ float wxr[256][2];
  __shared__ float brr[256];
  __shared__ float wxl[4];
  __shared__ float bll[2];

  const int tid = threadIdx.x;
  const int brow = blockIdx.x;
  const int ks = tid & 7;
  const int g  = tid >> 3;
  const int j0 = 2 + 4 * g;

  // persistent packed W: 4 rows x 16 k-pairs — VOLATILE pin (cannot be
  // duplicated/rematerialized; stays in VGPRs for the whole kernel)
  u32x4 wv[4][4];
  float2 wt[4];
#pragma unroll
  for (int r = 0; r < 4; ++r) {
    const uint32_t* p = Wp + (j0 + r) * 128 + 16 * ks;
#pragma unroll
    for (int c = 0; c < 4; ++c) wv[r][c] = *(const u32x4*)(p + 4 * c);
    wt[r] = *(const float2*)(Wtail + (j0 + r) * 2);
  }
#pragma unroll
  for (int r = 0; r < 4; ++r) {
#pragma unroll
    for (int c = 0; c < 4; ++c) asm volatile("" : "+v"(wv[r][c]));
    asm volatile("" : "+v"(wt[r]));
  }
  const float bro = b_ro[0];

  // --- staging ---
  if (tid < 256) {
    int row = tid >> 7, kp = tid & 127;
    wlp[row][PK(kp)] = Wp[row * 128 + kp];
    wxr[tid][0] = w_xr[2 * tid];
    wxr[tid][1] = w_xr[2 * tid + 1];
    brr[tid] = b_rr[tid];
  }
  if (tid < 4) {
    int row = tid >> 1;
    wlp[row][160 + (tid & 1)] = __float_as_uint(Wtail[row * 2 + (tid & 1)]);
    wxl[tid] = w_xl[tid];
  }
  if (tid < 2) bll[tid] = b_ll[tid];
  if (tid < 258) {                       // w_ro remapped to jj order
    int jj = (tid < 2) ? (256 + tid) : (tid - 2);
    wrol[jj] = w_ro[tid];
  }
  for (int idx = tid; idx < 336; idx += 512) ((uint32_t*)hbp)[idx] = 0u;

  // u,v for this batch row: uvb[t] = {u0,u1,v0,v1}
  for (int idx = tid; idx < 1600; idx += 512) {
    int t = idx >> 2, q = idx & 3;
    uint32_t e = (uint32_t)(brow * 800 + t * 2 + (q & 1));
    uint32_t o0, o1;
    if (q < 2) tf2x32(k0a, k0b, 0u, e, o0, o1);
    else       tf2x32(k1a, k1b, 0u, e, o0, o1);
    uvb[t][q] = xs[e] + noise_from_bits(o0 ^ o1);
  }
  __syncthreads();

  // per-chunk C generator (replaces gen_c kernel + HBM round-trip)
  auto gen_cbuf = [&](int cc) {
#pragma unroll
    for (int q = 0; q < 5; ++q) {
      int idx = tid + 512 * q;
      if (idx < 2064) {
        int s = idx / 258;
        int j = idx - 258 * s;
        int t = cc * 8 + s;
        uint32_t o0, o1;
        tf2x32(k2a, k2b, 0u, (uint32_t)(t * 132096 + brow * 258 + j), o0, o1);
        float nz = noise_from_bits(o0 ^ o1);
        float inj;
        int jj;
        if (j < 2) {
          inj = wxl[2 * j] * uvb[t][0] + wxl[2 * j + 1] * uvb[t][1] + bll[j];
          jj = 256 + j;
        } else {
          int jr = j - 2;
          inj = wxr[jr][0] * uvb[t][2] + wxr[jr][1] * uvb[t][3] + brr[jr];
          jj = jr;
        }
        cbuf[s][jj] = inj + nz;
      }
    }
  };

  gen_cbuf(0);
  __syncthreads();

  float hcur[4] = {0.f, 0.f, 0.f, 0.f};
  float hL0 = 0.f, hL1 = 0.f;

  float* gO = hsC + (size_t)brow * 103200;
  float* gZ = hsC + (size_t)52838400 + (size_t)brow * 400;

#pragma unroll 1
  for (int cc = 0; cc < 50; ++cc) {
#pragma unroll
    for (int s = 0; s < 8; ++s) {
      const int cur = s & 1, nxt = cur ^ 1;

      // main dot: 4 rows x 32 k as 64 v_pk_fma_f16
      uint32_t ac0 = 0u, ac1 = 0u, ac2 = 0u, ac3 = 0u;
#pragma unroll
      for (int c = 0; c < 4; ++c) {
        u32x4 hq = *(const u32x4*)&hbp[cur][20 * ks + 4 * c];
        u32x4 w0 = wv[0][c], w1 = wv[1][c], w2 = wv[2][c], w3 = wv[3][c];
        pkfma(ac0, w0.x, hq.x); pkfma(ac0, w0.y, hq.y);
        pkfma(ac0, w0.z, hq.z); pkfma(ac0, w0.w, hq.w);
        pkfma(ac1, w1.x, hq.x); pkfma(ac1, w1.y, hq.y);
        pkfma(ac1, w1.z, hq.z); pkfma(ac1, w1.w, hq.w);
        pkfma(ac2, w2.x, hq.x); pkfma(ac2, w2.y, hq.y);
        pkfma(ac2, w2.z, hq.z); pkfma(ac2, w2.w, hq.w);
        pkfma(ac3, w3.x, hq.x); pkfma(ac3, w3.y, hq.y);
        pkfma(ac3, w3.z, hq.z); pkfma(ac3, w3.w, hq.w);
      }
      float a0 = cvt2f(ac0);
      float a1 = cvt2f(ac1);
      float a2 = cvt2f(ac2);
      float a3 = cvt2f(ac3);

      // left rows (j=0,1): lanes 0..7 only
      float l0 = 0.f, l1 = 0.f;
      if (tid < 8) {
        uint32_t lc0 = 0u, lc1 = 0u;
#pragma unroll
        for (int c = 0; c < 4; ++c) {
          u32x4 hq = *(const u32x4*)&hbp[cur][20 * tid + 4 * c];
          u32x4 w0 = *(const u32x4*)&wlp[0][20 * tid + 4 * c];
          u32x4 w1 = *(const u32x4*)&wlp[1][20 * tid + 4 * c];
          pkfma(lc0, w0.x, hq.x); pkfma(lc0, w0.y, hq.y);
          pkfma(lc0, w0.z, hq.z); pkfma(lc0, w0.w, hq.w);
          pkfma(lc1, w1.x, hq.x); pkfma(lc1, w1.y, hq.y);
          pkfma(lc1, w1.z, hq.z); pkfma(lc1, w1.w, hq.w);
        }
        l0 = allred8(cvt2f(lc0));
        l1 = allred8(cvt2f(lc1));
      }

      a0 = allred8(a0); a1 = allred8(a1); a2 = allred8(a2); a3 = allred8(a3);

      const float t0 = __uint_as_float(hbp[cur][160]);
      const float t1 = __uint_as_float(hbp[cur][161]);

      // update right rows: lane ks==0 owns 4 rows
      if (ks == 0) {
        float4 cv = *(const float4*)&cbuf[s][4 * g];
        float pre0 = a0 + wt[0].x * t0 + wt[0].y * t1 + cv.x;
        float pre1 = a1 + wt[1].x * t0 + wt[1].y * t1 + cv.y;
        float pre2 = a2 + wt[2].x * t0 + wt[2].y * t1 + cv.z;
        float pre3 = a3 + wt[3].x * t0 + wt[3].y * t1 + cv.w;
        hcur[0] = 0.8f * hcur[0] + 0.2f * my_tanh(pre0);
        hcur[1] = 0.8f * hcur[1] + 0.2f * my_tanh(pre1);
        hcur[2] = 0.8f * hcur[2] + 0.2f * my_tanh(pre2);
        hcur[3] = 0.8f * hcur[3] + 0.2f * my_tanh(pre3);
        uint32_t p01 = packh2(hcur[0], hcur[1]);
        uint32_t p23 = packh2(hcur[2], hcur[3]);
        if (g == 63) {               // rows 254,255 packed; 256,257 f32 tail
          hbp[nxt][PK(127)] = p01;
          hbp[nxt][160] = __float_as_uint(hcur[2]);
          hbp[nxt][161] = __float_as_uint(hcur[3]);
        } else {
          hbp[nxt][PK(1 + 2 * g)] = p01;
          hbp[nxt][PK(2 + 2 * g)] = p23;
        }
        *(float4*)&sbuf[s][4 * g] = make_float4(hcur[0], hcur[1], hcur[2], hcur[3]);
      }

      // left updater: lane 0 owns rows 0,1 (h[0],h[1] -> pair kp=0)
      if (tid == 0) {
        float wl0t0 = __uint_as_float(wlp[0][160]);
        float wl0t1 = __uint_as_float(wlp[0][161]);
        float wl1t0 = __uint_as_float(wlp[1][160]);
        float wl1t1 = __uint_as_float(wlp[1][161]);
        float pre0 = l0 + wl0t0 * t0 + wl0t1 * t1 + cbuf[s][256];
        float pre1 = l1 + wl1t0 * t0 + wl1t1 * t1 + cbuf[s][257];
        hL0 = 0.8f * hL0 + 0.2f * my_tanh(pre0);
        hL1 = 0.8f * hL1 + 0.2f * my_tanh(pre1);
        hbp[nxt][0] = packh2(hL0, hL1);   // PK(0) == 0
        sbuf[s][256] = hL0;
        sbuf[s][257] = hL1;
      }

      step_barrier();
    }

    // flush sbuf -> hs (coalesced)
    const int fb = cc * 2064;
#pragma unroll
    for (int q = 0; q < 5; ++q) {
      int idx = tid + 512 * q;
      if (idx < 2064) {
        int s = idx / 258, j = idx - 258 * s;
        int jj = (j < 2) ? (256 + j) : (j - 2);
        gO[fb + idx] = sbuf[s][jj];
      }
    }

    // zs for the chunk's 8 timesteps: wave w handles s=w
    {
      int w = tid >> 6, lane = tid & 63;
      float zacc = 0.f;
#pragma unroll
      for (int q = 0; q < 5; ++q) {
        int jj = lane + 64 * q;
        if (jj < 258) zacc = fmaf(sbuf[w][jj], wrol[jj], zacc);
      }
#pragma unroll
      for (int m = 32; m >= 1; m >>= 1) zacc += __shfl_xor(zacc, m);
      if (lane == 0) gZ[cc * 8 + w] = zacc + bro;
    }

    // generate next C chunk in-place (pure VALU, no vmcnt dependency)
    if (cc < 49) gen_cbuf(cc + 1);
    step_barrier();
  }
}

// ---------------------------------------------------------------------------
extern "C" void kernel_launch(void* const* d_in, const int* in_sizes, int n_in,
                              void* d_out, int out_size, void* d_ws, size_t ws_size,
                              hipStream_t stream) {
  const float* xs   = (const float*)d_in[0];
  const float* w_ll = (const float*)d_in[1];
  const float* b_ll = (const float*)d_in[2];
  const float* w_rr = (const float*)d_in[3];
  const float* b_rr = (const float*)d_in[4];
  const float* w_lr = (const float*)d_in[5];
  const float* w_rl = (const float*)d_in[6];
  const float* w_xl = (const float*)d_in[7];
  const float* w_xr = (const float*)d_in[8];
  const float* w_ro = (const float*)d_in[9];
  const float* b_ro = (const float*)d_in[10];

  float* hs = (float*)d_out;                    // 512*400*258 (+ zs after)

  uint32_t* Wp  = (uint32_t*)d_ws;              // 258*128 = 33,024 u32
  float* Wtail  = (float*)(Wp + 33024);         // 516

  uint32_t nk[3][2];
  for (uint32_t i = 0; i < 3; ++i) {
    uint32_t o0, o1;
    tf2x32(0u, 42u, 0u, i, o0, o1);
    nk[i][0] = o0; nk[i][1] = o1;
  }

  build_w_kernel<<<129, 256, 0, stream>>>(w_ll, w_rl, w_lr, w_rr, Wp, Wtail);
  rnn_scan_kernel<<<512, 512, 0, stream>>>(Wp, Wtail, hs, w_ro, b_ro, xs,
                                           w_xl, w_xr, b_ll, b_rr,
                                           nk[0][0], nk[0][1], nk[1][0], nk[1][1],
                                           nk[2][0], nk[2][1]);
}

// Round 11
// 1262.772 us; speedup vs baseline: 1.3237x; 1.3237x over previous
//
#include <hip/hip_runtime.h>
#include <stdint.h>
#include <stddef.h>

// ---------------------------------------------------------------------------
// TwoHemiRNNTanh_asymmetric_single_readout  (B=512, T=400, hidden 258)
// R11: geometry fix for W residency. 256 blocks x 1024 thr, 2 batch rows per
// block. Thread (g,ks): 2 W-rows (j0=2+2g) x 32k -> W = 32 dwords/thread
// (half of R8/R10), peak VGPR pressure ~100 < 128 budget -> W stays resident
// without pin hacks (R9/R10's 64-dword W + pins => spill storms, 1.4GB TCC).
// Kept from R8/R10: PK skew, asm v_pk_fma_f16, allred8, lgkm-only barriers,
// fused uv/C generation, zs in chunk flush.
// ---------------------------------------------------------------------------

typedef uint32_t u32x4 __attribute__((ext_vector_type(4)));
typedef __fp16   f16x2 __attribute__((ext_vector_type(2)));

#define TF_ROUND(x0, x1, r) { x0 += x1; x1 = ((x1) << (r)) | ((x1) >> (32 - (r))); x1 ^= x0; }

__host__ __device__ inline void tf2x32(uint32_t k0, uint32_t k1, uint32_t x0, uint32_t x1,
                                       uint32_t& o0, uint32_t& o1) {
  uint32_t ks2 = k0 ^ k1 ^ 0x1BD11BDAu;
  x0 += k0; x1 += k1;
  TF_ROUND(x0, x1, 13) TF_ROUND(x0, x1, 15) TF_ROUND(x0, x1, 26) TF_ROUND(x0, x1, 6)
  x0 += k1; x1 += ks2 + 1u;
  TF_ROUND(x0, x1, 17) TF_ROUND(x0, x1, 29) TF_ROUND(x0, x1, 16) TF_ROUND(x0, x1, 24)
  x0 += ks2; x1 += k0 + 2u;
  TF_ROUND(x0, x1, 13) TF_ROUND(x0, x1, 15) TF_ROUND(x0, x1, 26) TF_ROUND(x0, x1, 6)
  x0 += k0; x1 += k1 + 3u;
  TF_ROUND(x0, x1, 17) TF_ROUND(x0, x1, 29) TF_ROUND(x0, x1, 16) TF_ROUND(x0, x1, 24)
  x0 += k1; x1 += ks2 + 4u;
  TF_ROUND(x0, x1, 13) TF_ROUND(x0, x1, 15) TF_ROUND(x0, x1, 26) TF_ROUND(x0, x1, 6)
  x0 += ks2; x1 += k0 + 5u;
  o0 = x0; o1 = x1;
}

__device__ __forceinline__ float jax_erfinv(float x) {
  float w = -log1pf(-x * x);
  float p;
  if (w < 5.0f) {
    w -= 2.5f;
    p = 2.81022636e-08f;
    p = fmaf(p, w, 3.43273939e-07f);
    p = fmaf(p, w, -3.5233877e-06f);
    p = fmaf(p, w, -4.39150654e-06f);
    p = fmaf(p, w, 0.00021858087f);
    p = fmaf(p, w, -0.00125372503f);
    p = fmaf(p, w, -0.00417768164f);
    p = fmaf(p, w, 0.246640727f);
    p = fmaf(p, w, 1.50140941f);
  } else {
    w = sqrtf(w) - 3.0f;
    p = -0.000200214257f;
    p = fmaf(p, w, 0.000100950558f);
    p = fmaf(p, w, 0.00134934322f);
    p = fmaf(p, w, -0.00367342844f);
    p = fmaf(p, w, 0.00573950773f);
    p = fmaf(p, w, -0.0076224613f);
    p = fmaf(p, w, 0.00943887047f);
    p = fmaf(p, w, 1.00167406f);
    p = fmaf(p, w, 2.83297682f);
  }
  return p * x;
}

__device__ __forceinline__ float uni_from_bits(uint32_t bits) {
  float f = __uint_as_float((bits >> 9) | 0x3f800000u) - 1.0f;
  float x = f * 2.0f + (-0.99999994f);
  return fmaxf(-0.99999994f, x);
}

__device__ __forceinline__ float noise_from_bits(uint32_t bits) {
  float n = 1.41421356f * jax_erfinv(uni_from_bits(bits));
  return 0.15811388f * n;   // sqrt(2/A)*SIG = sqrt(10)*0.05
}

__device__ __forceinline__ float my_tanh(float x) {
  float e = __expf(2.0f * x);
  return 1.0f - 2.0f / (e + 1.0f);
}

__device__ __forceinline__ uint32_t packh2(float a, float b) {
  f16x2 h = __builtin_amdgcn_cvt_pkrtz(a, b);
  return __builtin_bit_cast(uint32_t, h);
}

__device__ __forceinline__ void pkfma(uint32_t& acc, uint32_t w, uint32_t h) {
  asm("v_pk_fma_f16 %0, %1, %2, %0" : "+v"(acc) : "v"(w), "v"(h));
}

__device__ __forceinline__ float cvt2f(uint32_t a) {
  f16x2 v = __builtin_bit_cast(f16x2, a);
  return (float)v.x + (float)v.y;
}

// LDS-only barrier (no vmcnt drain)
__device__ __forceinline__ void step_barrier() {
  asm volatile("s_waitcnt lgkmcnt(0)" ::: "memory");
  __builtin_amdgcn_s_barrier();
}

// 8-lane allreduce: xor1,xor2 via DPP quad_perm (VALU); xor4 via ds_swizzle.
__device__ __forceinline__ float allred8(float x) {
  int t = __builtin_amdgcn_update_dpp(0, __float_as_int(x), 0xB1, 0xF, 0xF, true);
  x += __int_as_float(t);
  t = __builtin_amdgcn_update_dpp(0, __float_as_int(x), 0x4E, 0xF, 0xF, true);
  x += __int_as_float(t);
  t = __builtin_amdgcn_ds_swizzle(__float_as_int(x), 0x101F);
  x += __int_as_float(t);
  return x;
}

// packed-slot skew: kp in [0,128) -> 20*(kp>>4) + (kp&15); spans 160 dwords.
#define PK(kp) (20 * ((kp) >> 4) + ((kp) & 15))

#define PKQ(acc, wq, hq) { pkfma(acc, (wq).x, (hq).x); pkfma(acc, (wq).y, (hq).y); \
                           pkfma(acc, (wq).z, (hq).z); pkfma(acc, (wq).w, (hq).w); }

// ---------------------------------------------------------------------------
__device__ __forceinline__ float wval(int j, int k,
    const float* w_ll, const float* w_rl, const float* w_lr, const float* w_rr) {
  if (j < 2) return (k < 2) ? w_ll[j * 2 + k] : w_rl[j * 256 + (k - 2)];
  return (k < 2) ? w_lr[(j - 2) * 2 + k] : w_rr[(j - 2) * 256 + (k - 2)];
}

// Wp: packed f16 pairs [258][128]; Wtail: f32 [258][2] (k=256,257).
__global__ __launch_bounds__(256) void build_w_kernel(
    const float* __restrict__ w_ll, const float* __restrict__ w_rl,
    const float* __restrict__ w_lr, const float* __restrict__ w_rr,
    uint32_t* __restrict__ Wp, float* __restrict__ Wtail) {
  int i = blockIdx.x * 256 + threadIdx.x;
  if (i < 258 * 128) {
    int j = i >> 7, kp = i & 127;
    float v0 = wval(j, 2 * kp, w_ll, w_rl, w_lr, w_rr);
    float v1 = wval(j, 2 * kp + 1, w_ll, w_rl, w_lr, w_rr);
    Wp[i] = packh2(v0, v1);
  }
  if (i < 516) {
    int j = i >> 1, k = 256 + (i & 1);
    Wtail[i] = wval(j, k, w_ll, w_rl, w_lr, w_rr);
  }
}

// ---------------------------------------------------------------------------
// K_scan: 256 blocks x 1024 thr, 2 batch rows/block (b0, b0+1).
// Thread (g=tid>>3, ks=tid&7): W rows j0=2+2g, j0+1; k in [32ks,32ks+32).
// W = 8 u32x4 (32 VGPR), naturally resident. 4 accumulators (2 rows x 2 batch).
// Lane ks=b updates batch b. Left rows: lanes 0-7 batch 0, lanes 8-15 batch 1.
// ---------------------------------------------------------------------------
__global__ __launch_bounds__(1024, 4) void rnn_scan_kernel(
    const uint32_t* __restrict__ Wp, const float* __restrict__ Wtail,
    float* __restrict__ hsC,
    const float* __restrict__ w_ro, const float* __restrict__ b_ro,
    const float* __restrict__ xs,
    const float* __restrict__ w_xl, const float* __restrict__ w_xr,
    const float* __restrict__ b_ll, const float* __restrict__ b_rr,
    uint32_t k0a, uint32_t k0b, uint32_t k1a, uint32_t k1b,
    uint32_t k2a, uint32_t k2b) {
  __shared__ __align__(16) uint32_t hbp[2][2][168];   // [dbuf][batch][slot]
  __shared__ __align__(16) uint32_t wlp[2][168];      // left W rows 0,1
  __shared__ __align__(16) float cbuf[2][8][260];     // [batch][s][jj]
  __shared__ __align__(16) float sbuf[2][8][260];
  __shared__ float wrol[260];
  __shared__ float uvb[400][2][4];                    // [t][batch][u0,u1,v0,v1]
  __shared__ float wxr[256][2];
  __shared__ float brr[256];
  __shared__ float wxl[4];
  __shared__ float bll[2];

  const int tid = threadIdx.x;
  const int b0 = blockIdx.x * 2;
  const int ks = tid & 7;
  const int g  = tid >> 3;          // [0,128)
  const int j0 = 2 + 2 * g;

  // persistent W: 2 rows x 8 k-pair quads = 32 dwords (fits; no pins)
  u32x4 w0q[4], w1q[4];
  {
    const uint32_t* p0 = Wp + (size_t)j0 * 128 + 16 * ks;
    const uint32_t* p1 = p0 + 128;
#pragma unroll
    for (int c = 0; c < 4; ++c) {
      w0q[c] = *(const u32x4*)(p0 + 4 * c);
      w1q[c] = *(const u32x4*)(p1 + 4 * c);
    }
  }
  const float2 wt0 = *(const float2*)(Wtail + (size_t)j0 * 2);
  const float2 wt1 = *(const float2*)(Wtail + (size_t)j0 * 2 + 2);
  const float bro = b_ro[0];

  // --- staging ---
  if (tid < 256) {
    int row = tid >> 7, kp = tid & 127;
    wlp[row][PK(kp)] = Wp[row * 128 + kp];
    wxr[tid][0] = w_xr[2 * tid];
    wxr[tid][1] = w_xr[2 * tid + 1];
    brr[tid] = b_rr[tid];
  }
  if (tid < 4) {
    int row = tid >> 1;
    wlp[row][160 + (tid & 1)] = __float_as_uint(Wtail[row * 2 + (tid & 1)]);
    wxl[tid] = w_xl[tid];
  }
  if (tid < 2) bll[tid] = b_ll[tid];
  if (tid < 258) {
    int jj = (tid < 2) ? (256 + tid) : (tid - 2);
    wrol[jj] = w_ro[tid];
  }
  for (int idx = tid; idx < 672; idx += 1024) ((uint32_t*)hbp)[idx] = 0u;

  // u,v for both batch rows: uvb[t][b] = {u0,u1,v0,v1}
  for (int idx = tid; idx < 3200; idx += 1024) {
    int t = idx >> 3, rem = idx & 7;
    int b = rem >> 2, q = rem & 3;
    uint32_t e = (uint32_t)((b0 + b) * 800 + t * 2 + (q & 1));
    uint32_t o0, o1;
    if (q < 2) tf2x32(k0a, k0b, 0u, e, o0, o1);
    else       tf2x32(k1a, k1b, 0u, e, o0, o1);
    uvb[t][b][q] = xs[e] + noise_from_bits(o0 ^ o1);
  }
  __syncthreads();

  // per-chunk C generator: 2 batch rows x 8 steps x 258 = 4128 elements
  auto gen_cbuf = [&](int cc) {
#pragma unroll
    for (int q = 0; q < 5; ++q) {
      int idx = tid + 1024 * q;
      if (idx < 4128) {
        int ro = idx >= 2064 ? 1 : 0;
        int ii = idx - 2064 * ro;
        int s = ii / 258;
        int j = ii - 258 * s;
        int t = cc * 8 + s;
        uint32_t o0, o1;
        tf2x32(k2a, k2b, 0u, (uint32_t)(t * 132096 + (b0 + ro) * 258 + j), o0, o1);
        float nz = noise_from_bits(o0 ^ o1);
        float inj;
        int jj;
        if (j < 2) {
          inj = wxl[2 * j] * uvb[t][ro][0] + wxl[2 * j + 1] * uvb[t][ro][1] + bll[j];
          jj = 256 + j;
        } else {
          int jr = j - 2;
          inj = wxr[jr][0] * uvb[t][ro][2] + wxr[jr][1] * uvb[t][ro][3] + brr[jr];
          jj = jr;
        }
        cbuf[ro][s][jj] = inj + nz;
      }
    }
  };

  gen_cbuf(0);
  __syncthreads();

  float hc0 = 0.f, hc1 = 0.f;       // rows j0, j0+1 of batch `ks` (ks<2 lanes)
  float hL0 = 0.f, hL1 = 0.f;       // left rows (lanes 0 and 8: batch tid>>3)

  float* gO0 = hsC + (size_t)b0 * 103200;
  float* gO1 = gO0 + 103200;
  float* gZ  = hsC + (size_t)52838400 + (size_t)b0 * 400;

#pragma unroll 1
  for (int cc = 0; cc < 50; ++cc) {
#pragma unroll
    for (int s = 0; s < 8; ++s) {
      const int cur = s & 1, nxt = cur ^ 1;

      // main dot: 2 rows x 2 batch x 32k = 64 v_pk_fma_f16
      uint32_t a00 = 0u, a01 = 0u, a10 = 0u, a11 = 0u;
#pragma unroll
      for (int c = 0; c < 4; ++c) {
        u32x4 hq0 = *(const u32x4*)&hbp[cur][0][20 * ks + 4 * c];
        u32x4 hq1 = *(const u32x4*)&hbp[cur][1][20 * ks + 4 * c];
        PKQ(a00, w0q[c], hq0) PKQ(a01, w1q[c], hq0)
        PKQ(a10, w0q[c], hq1) PKQ(a11, w1q[c], hq1)
      }

      // left rows: lanes 0-7 (batch 0), lanes 8-15 (batch 1)
      float l0 = 0.f, l1 = 0.f;
      if (tid < 16) {
        const int lb = tid >> 3;
        uint32_t lc0 = 0u, lc1 = 0u;
#pragma unroll
        for (int c = 0; c < 4; ++c) {
          u32x4 hq = *(const u32x4*)&hbp[cur][lb][20 * ks + 4 * c];
          u32x4 wl0 = *(const u32x4*)&wlp[0][20 * ks + 4 * c];
          u32x4 wl1 = *(const u32x4*)&wlp[1][20 * ks + 4 * c];
          PKQ(lc0, wl0, hq) PKQ(lc1, wl1, hq)
        }
        l0 = allred8(cvt2f(lc0));
        l1 = allred8(cvt2f(lc1));
      }

      float r00 = allred8(cvt2f(a00));
      float r01 = allred8(cvt2f(a01));
      float r10 = allred8(cvt2f(a10));
      float r11 = allred8(cvt2f(a11));

      // update right rows: lane ks=b owns batch b, rows j0,j0+1
      if (ks < 2) {
        float d0 = ks ? r10 : r00;
        float d1 = ks ? r11 : r01;
        float t0 = __uint_as_float(hbp[cur][ks][160]);
        float t1 = __uint_as_float(hbp[cur][ks][161]);
        float2 cv = *(const float2*)&cbuf[ks][s][2 * g];
        float pre0 = d0 + wt0.x * t0 + wt0.y * t1 + cv.x;
        float pre1 = d1 + wt1.x * t0 + wt1.y * t1 + cv.y;
        hc0 = 0.8f * hc0 + 0.2f * my_tanh(pre0);
        hc1 = 0.8f * hc1 + 0.2f * my_tanh(pre1);
        *(float2*)&sbuf[ks][s][2 * g] = make_float2(hc0, hc1);
        if (g == 127) {            // rows 256,257 -> f32 tail slots
          hbp[nxt][ks][160] = __float_as_uint(hc0);
          hbp[nxt][ks][161] = __float_as_uint(hc1);
        } else {
          hbp[nxt][ks][PK(g + 1)] = packh2(hc0, hc1);
        }
      }

      // left updaters: lane 0 (batch 0) and lane 8 (batch 1)
      if (tid < 16 && ks == 0) {
        const int lb = tid >> 3;
        float wl0t0 = __uint_as_float(wlp[0][160]);
        float wl0t1 = __uint_as_float(wlp[0][161]);
        float wl1t0 = __uint_as_float(wlp[1][160]);
        float wl1t1 = __uint_as_float(wlp[1][161]);
        float t0 = __uint_as_float(hbp[cur][lb][160]);
        float t1 = __uint_as_float(hbp[cur][lb][161]);
        float pre0 = l0 + wl0t0 * t0 + wl0t1 * t1 + cbuf[lb][s][256];
        float pre1 = l1 + wl1t0 * t0 + wl1t1 * t1 + cbuf[lb][s][257];
        hL0 = 0.8f * hL0 + 0.2f * my_tanh(pre0);
        hL1 = 0.8f * hL1 + 0.2f * my_tanh(pre1);
        hbp[nxt][lb][0] = packh2(hL0, hL1);   // PK(0) == 0 -> h[0],h[1]
        sbuf[lb][s][256] = hL0;
        sbuf[lb][s][257] = hL1;
      }

      step_barrier();
    }

    // flush sbuf -> hs (coalesced, both batch rows)
    const int fb = cc * 2064;
#pragma unroll
    for (int q = 0; q < 5; ++q) {
      int idx = tid + 1024 * q;
      if (idx < 4128) {
        int ro = idx >= 2064 ? 1 : 0;
        int ii = idx - 2064 * ro;
        int s = ii / 258, j = ii - 258 * s;
        int jj = (j < 2) ? (256 + j) : (j - 2);
        float vv = sbuf[ro][s][jj];
        if (ro) gO1[fb + ii] = vv; else gO0[fb + ii] = vv;
      }
    }

    // zs: wave w in [0,16) handles (row = w>>3, s = w&7)
    {
      int w = tid >> 6, lane = tid & 63;
      int ro = w >> 3, s = w & 7;
      float zacc = 0.f;
#pragma unroll
      for (int q = 0; q < 5; ++q) {
        int jj = lane + 64 * q;
        if (jj < 258) zacc = fmaf(sbuf[ro][s][jj], wrol[jj], zacc);
      }
#pragma unroll
      for (int m = 32; m >= 1; m >>= 1) zacc += __shfl_xor(zacc, m);
      if (lane == 0) gZ[ro * 400 + cc * 8 + s] = zacc + bro;
    }

    // generate next C chunk (pure VALU/LDS, no vmcnt dependency)
    if (cc < 49) gen_cbuf(cc + 1);
    step_barrier();
  }
}

// ---------------------------------------------------------------------------
extern "C" void kernel_launch(void* const* d_in, const int* in_sizes, int n_in,
                              void* d_out, int out_size, void* d_ws, size_t ws_size,
                              hipStream_t stream) {
  const float* xs   = (const float*)d_in[0];
  const float* w_ll = (const float*)d_in[1];
  const float* b_ll = (const float*)d_in[2];
  const float* w_rr = (const float*)d_in[3];
  const float* b_rr = (const float*)d_in[4];
  const float* w_lr = (const float*)d_in[5];
  const float* w_rl = (const float*)d_in[6];
  const float* w_xl = (const float*)d_in[7];
  const float* w_xr = (const float*)d_in[8];
  const float* w_ro = (const float*)d_in[9];
  const float* b_ro = (const float*)d_in[10];

  float* hs = (float*)d_out;                    // 512*400*258 (+ zs after)

  uint32_t* Wp  = (uint32_t*)d_ws;              // 258*128 = 33,024 u32
  float* Wtail  = (float*)(Wp + 33024);         // 516

  uint32_t nk[3][2];
  for (uint32_t i = 0; i < 3; ++i) {
    uint32_t o0, o1;
    tf2x32(0u, 42u, 0u, i, o0, o1);
    nk[i][0] = o0; nk[i][1] = o1;
  }

  build_w_kernel<<<129, 256, 0, stream>>>(w_ll, w_rl, w_lr, w_rr, Wp, Wtail);
  rnn_scan_kernel<<<256, 1024, 0, stream>>>(Wp, Wtail, hs, w_ro, b_ro, xs,
                                            w_xl, w_xr, b_ll, b_rr,
                                            nk[0][0], nk[0][1], nk[1][0], nk[1][1],
                                            nk[2][0], nk[2][1]);
}

// Round 12
// 1262.324 us; speedup vs baseline: 1.3241x; 1.0004x over previous
//
#include <hip/hip_runtime.h>
#include <stdint.h>
#include <stddef.h>

// ---------------------------------------------------------------------------
// TwoHemiRNNTanh_asymmetric_single_readout  (B=512, T=400, hidden 258)
// R12 = R11 + amdgpu_waves_per_eu(4,4). R8-R11 all showed VGPR_Count=64 with
// massive excess FETCH: LLVM targets 8 waves/EU (VGPR<=64) even though 54KB
// LDS caps us at 1 block = 4 waves/EU, so W spills to scratch and the per-step
// reloads dominate. min=max=4 unlocks the 128-VGPR budget at unchanged real
// occupancy. Everything else identical to R11.
// ---------------------------------------------------------------------------

typedef uint32_t u32x4 __attribute__((ext_vector_type(4)));
typedef __fp16   f16x2 __attribute__((ext_vector_type(2)));

#define TF_ROUND(x0, x1, r) { x0 += x1; x1 = ((x1) << (r)) | ((x1) >> (32 - (r))); x1 ^= x0; }

__host__ __device__ inline void tf2x32(uint32_t k0, uint32_t k1, uint32_t x0, uint32_t x1,
                                       uint32_t& o0, uint32_t& o1) {
  uint32_t ks2 = k0 ^ k1 ^ 0x1BD11BDAu;
  x0 += k0; x1 += k1;
  TF_ROUND(x0, x1, 13) TF_ROUND(x0, x1, 15) TF_ROUND(x0, x1, 26) TF_ROUND(x0, x1, 6)
  x0 += k1; x1 += ks2 + 1u;
  TF_ROUND(x0, x1, 17) TF_ROUND(x0, x1, 29) TF_ROUND(x0, x1, 16) TF_ROUND(x0, x1, 24)
  x0 += ks2; x1 += k0 + 2u;
  TF_ROUND(x0, x1, 13) TF_ROUND(x0, x1, 15) TF_ROUND(x0, x1, 26) TF_ROUND(x0, x1, 6)
  x0 += k0; x1 += k1 + 3u;
  TF_ROUND(x0, x1, 17) TF_ROUND(x0, x1, 29) TF_ROUND(x0, x1, 16) TF_ROUND(x0, x1, 24)
  x0 += k1; x1 += ks2 + 4u;
  TF_ROUND(x0, x1, 13) TF_ROUND(x0, x1, 15) TF_ROUND(x0, x1, 26) TF_ROUND(x0, x1, 6)
  x0 += ks2; x1 += k0 + 5u;
  o0 = x0; o1 = x1;
}

__device__ __forceinline__ float jax_erfinv(float x) {
  float w = -log1pf(-x * x);
  float p;
  if (w < 5.0f) {
    w -= 2.5f;
    p = 2.81022636e-08f;
    p = fmaf(p, w, 3.43273939e-07f);
    p = fmaf(p, w, -3.5233877e-06f);
    p = fmaf(p, w, -4.39150654e-06f);
    p = fmaf(p, w, 0.00021858087f);
    p = fmaf(p, w, -0.00125372503f);
    p = fmaf(p, w, -0.00417768164f);
    p = fmaf(p, w, 0.246640727f);
    p = fmaf(p, w, 1.50140941f);
  } else {
    w = sqrtf(w) - 3.0f;
    p = -0.000200214257f;
    p = fmaf(p, w, 0.000100950558f);
    p = fmaf(p, w, 0.00134934322f);
    p = fmaf(p, w, -0.00367342844f);
    p = fmaf(p, w, 0.00573950773f);
    p = fmaf(p, w, -0.0076224613f);
    p = fmaf(p, w, 0.00943887047f);
    p = fmaf(p, w, 1.00167406f);
    p = fmaf(p, w, 2.83297682f);
  }
  return p * x;
}

__device__ __forceinline__ float uni_from_bits(uint32_t bits) {
  float f = __uint_as_float((bits >> 9) | 0x3f800000u) - 1.0f;
  float x = f * 2.0f + (-0.99999994f);
  return fmaxf(-0.99999994f, x);
}

__device__ __forceinline__ float noise_from_bits(uint32_t bits) {
  float n = 1.41421356f * jax_erfinv(uni_from_bits(bits));
  return 0.15811388f * n;   // sqrt(2/A)*SIG = sqrt(10)*0.05
}

__device__ __forceinline__ float my_tanh(float x) {
  float e = __expf(2.0f * x);
  return 1.0f - 2.0f / (e + 1.0f);
}

__device__ __forceinline__ uint32_t packh2(float a, float b) {
  f16x2 h = __builtin_amdgcn_cvt_pkrtz(a, b);
  return __builtin_bit_cast(uint32_t, h);
}

__device__ __forceinline__ void pkfma(uint32_t& acc, uint32_t w, uint32_t h) {
  asm("v_pk_fma_f16 %0, %1, %2, %0" : "+v"(acc) : "v"(w), "v"(h));
}

__device__ __forceinline__ float cvt2f(uint32_t a) {
  f16x2 v = __builtin_bit_cast(f16x2, a);
  return (float)v.x + (float)v.y;
}

// LDS-only barrier (no vmcnt drain)
__device__ __forceinline__ void step_barrier() {
  asm volatile("s_waitcnt lgkmcnt(0)" ::: "memory");
  __builtin_amdgcn_s_barrier();
}

// 8-lane allreduce: xor1,xor2 via DPP quad_perm (VALU); xor4 via ds_swizzle.
__device__ __forceinline__ float allred8(float x) {
  int t = __builtin_amdgcn_update_dpp(0, __float_as_int(x), 0xB1, 0xF, 0xF, true);
  x += __int_as_float(t);
  t = __builtin_amdgcn_update_dpp(0, __float_as_int(x), 0x4E, 0xF, 0xF, true);
  x += __int_as_float(t);
  t = __builtin_amdgcn_ds_swizzle(__float_as_int(x), 0x101F);
  x += __int_as_float(t);
  return x;
}

// packed-slot skew: kp in [0,128) -> 20*(kp>>4) + (kp&15); spans 160 dwords.
#define PK(kp) (20 * ((kp) >> 4) + ((kp) & 15))

#define PKQ(acc, wq, hq) { pkfma(acc, (wq).x, (hq).x); pkfma(acc, (wq).y, (hq).y); \
                           pkfma(acc, (wq).z, (hq).z); pkfma(acc, (wq).w, (hq).w); }

// ---------------------------------------------------------------------------
__device__ __forceinline__ float wval(int j, int k,
    const float* w_ll, const float* w_rl, const float* w_lr, const float* w_rr) {
  if (j < 2) return (k < 2) ? w_ll[j * 2 + k] : w_rl[j * 256 + (k - 2)];
  return (k < 2) ? w_lr[(j - 2) * 2 + k] : w_rr[(j - 2) * 256 + (k - 2)];
}

// Wp: packed f16 pairs [258][128]; Wtail: f32 [258][2] (k=256,257).
__global__ __launch_bounds__(256) void build_w_kernel(
    const float* __restrict__ w_ll, const float* __restrict__ w_rl,
    const float* __restrict__ w_lr, const float* __restrict__ w_rr,
    uint32_t* __restrict__ Wp, float* __restrict__ Wtail) {
  int i = blockIdx.x * 256 + threadIdx.x;
  if (i < 258 * 128) {
    int j = i >> 7, kp = i & 127;
    float v0 = wval(j, 2 * kp, w_ll, w_rl, w_lr, w_rr);
    float v1 = wval(j, 2 * kp + 1, w_ll, w_rl, w_lr, w_rr);
    Wp[i] = packh2(v0, v1);
  }
  if (i < 516) {
    int j = i >> 1, k = 256 + (i & 1);
    Wtail[i] = wval(j, k, w_ll, w_rl, w_lr, w_rr);
  }
}

// ---------------------------------------------------------------------------
// K_scan: 256 blocks x 1024 thr, 2 batch rows/block (b0, b0+1).
// Thread (g=tid>>3, ks=tid&7): W rows j0=2+2g, j0+1; k in [32ks,32ks+32).
// W = 8 u32x4 (32 VGPR). waves_per_eu(4,4): allocator budget = 128 VGPR
// (LDS already caps occupancy at 1 block/CU = 4 waves/EU, so no real loss).
// ---------------------------------------------------------------------------
__global__ __attribute__((amdgpu_flat_work_group_size(1024, 1024),
                          amdgpu_waves_per_eu(4, 4)))
void rnn_scan_kernel(
    const uint32_t* __restrict__ Wp, const float* __restrict__ Wtail,
    float* __restrict__ hsC,
    const float* __restrict__ w_ro, const float* __restrict__ b_ro,
    const float* __restrict__ xs,
    const float* __restrict__ w_xl, const float* __restrict__ w_xr,
    const float* __restrict__ b_ll, const float* __restrict__ b_rr,
    uint32_t k0a, uint32_t k0b, uint32_t k1a, uint32_t k1b,
    uint32_t k2a, uint32_t k2b) {
  __shared__ __align__(16) uint32_t hbp[2][2][168];   // [dbuf][batch][slot]
  __shared__ __align__(16) uint32_t wlp[2][168];      // left W rows 0,1
  __shared__ __align__(16) float cbuf[2][8][260];     // [batch][s][jj]
  __shared__ __align__(16) float sbuf[2][8][260];
  __shared__ float wrol[260];
  __shared__ float uvb[400][2][4];                    // [t][batch][u0,u1,v0,v1]
  __shared__ float wxr[256][2];
  __shared__ float brr[256];
  __shared__ float wxl[4];
  __shared__ float bll[2];

  const int tid = threadIdx.x;
  const int b0 = blockIdx.x * 2;
  const int ks = tid & 7;
  const int g  = tid >> 3;          // [0,128)
  const int j0 = 2 + 2 * g;

  // persistent W: 2 rows x 8 k-pair quads = 32 dwords
  u32x4 w0q[4], w1q[4];
  {
    const uint32_t* p0 = Wp + (size_t)j0 * 128 + 16 * ks;
    const uint32_t* p1 = p0 + 128;
#pragma unroll
    for (int c = 0; c < 4; ++c) {
      w0q[c] = *(const u32x4*)(p0 + 4 * c);
      w1q[c] = *(const u32x4*)(p1 + 4 * c);
    }
  }
  const float2 wt0 = *(const float2*)(Wtail + (size_t)j0 * 2);
  const float2 wt1 = *(const float2*)(Wtail + (size_t)j0 * 2 + 2);
  const float bro = b_ro[0];

  // --- staging ---
  if (tid < 256) {
    int row = tid >> 7, kp = tid & 127;
    wlp[row][PK(kp)] = Wp[row * 128 + kp];
    wxr[tid][0] = w_xr[2 * tid];
    wxr[tid][1] = w_xr[2 * tid + 1];
    brr[tid] = b_rr[tid];
  }
  if (tid < 4) {
    int row = tid >> 1;
    wlp[row][160 + (tid & 1)] = __float_as_uint(Wtail[row * 2 + (tid & 1)]);
    wxl[tid] = w_xl[tid];
  }
  if (tid < 2) bll[tid] = b_ll[tid];
  if (tid < 258) {
    int jj = (tid < 2) ? (256 + tid) : (tid - 2);
    wrol[jj] = w_ro[tid];
  }
  for (int idx = tid; idx < 672; idx += 1024) ((uint32_t*)hbp)[idx] = 0u;

  // u,v for both batch rows: uvb[t][b] = {u0,u1,v0,v1}
  for (int idx = tid; idx < 3200; idx += 1024) {
    int t = idx >> 3, rem = idx & 7;
    int b = rem >> 2, q = rem & 3;
    uint32_t e = (uint32_t)((b0 + b) * 800 + t * 2 + (q & 1));
    uint32_t o0, o1;
    if (q < 2) tf2x32(k0a, k0b, 0u, e, o0, o1);
    else       tf2x32(k1a, k1b, 0u, e, o0, o1);
    uvb[t][b][q] = xs[e] + noise_from_bits(o0 ^ o1);
  }
  __syncthreads();

  // per-chunk C generator: 2 batch rows x 8 steps x 258 = 4128 elements
  auto gen_cbuf = [&](int cc) {
#pragma unroll
    for (int q = 0; q < 5; ++q) {
      int idx = tid + 1024 * q;
      if (idx < 4128) {
        int ro = idx >= 2064 ? 1 : 0;
        int ii = idx - 2064 * ro;
        int s = ii / 258;
        int j = ii - 258 * s;
        int t = cc * 8 + s;
        uint32_t o0, o1;
        tf2x32(k2a, k2b, 0u, (uint32_t)(t * 132096 + (b0 + ro) * 258 + j), o0, o1);
        float nz = noise_from_bits(o0 ^ o1);
        float inj;
        int jj;
        if (j < 2) {
          inj = wxl[2 * j] * uvb[t][ro][0] + wxl[2 * j + 1] * uvb[t][ro][1] + bll[j];
          jj = 256 + j;
        } else {
          int jr = j - 2;
          inj = wxr[jr][0] * uvb[t][ro][2] + wxr[jr][1] * uvb[t][ro][3] + brr[jr];
          jj = jr;
        }
        cbuf[ro][s][jj] = inj + nz;
      }
    }
  };

  gen_cbuf(0);
  __syncthreads();

  float hc0 = 0.f, hc1 = 0.f;       // rows j0, j0+1 of batch `ks` (ks<2 lanes)
  float hL0 = 0.f, hL1 = 0.f;       // left rows (lanes 0 and 8: batch tid>>3)

  float* gO0 = hsC + (size_t)b0 * 103200;
  float* gO1 = gO0 + 103200;
  float* gZ  = hsC + (size_t)52838400 + (size_t)b0 * 400;

#pragma unroll 1
  for (int cc = 0; cc < 50; ++cc) {
#pragma unroll
    for (int s = 0; s < 8; ++s) {
      const int cur = s & 1, nxt = cur ^ 1;

      // main dot: 2 rows x 2 batch x 32k = 64 v_pk_fma_f16
      uint32_t a00 = 0u, a01 = 0u, a10 = 0u, a11 = 0u;
#pragma unroll
      for (int c = 0; c < 4; ++c) {
        u32x4 hq0 = *(const u32x4*)&hbp[cur][0][20 * ks + 4 * c];
        u32x4 hq1 = *(const u32x4*)&hbp[cur][1][20 * ks + 4 * c];
        PKQ(a00, w0q[c], hq0) PKQ(a01, w1q[c], hq0)
        PKQ(a10, w0q[c], hq1) PKQ(a11, w1q[c], hq1)
      }

      // left rows: lanes 0-7 (batch 0), lanes 8-15 (batch 1)
      float l0 = 0.f, l1 = 0.f;
      if (tid < 16) {
        const int lb = tid >> 3;
        uint32_t lc0 = 0u, lc1 = 0u;
#pragma unroll
        for (int c = 0; c < 4; ++c) {
          u32x4 hq = *(const u32x4*)&hbp[cur][lb][20 * ks + 4 * c];
          u32x4 wl0 = *(const u32x4*)&wlp[0][20 * ks + 4 * c];
          u32x4 wl1 = *(const u32x4*)&wlp[1][20 * ks + 4 * c];
          PKQ(lc0, wl0, hq) PKQ(lc1, wl1, hq)
        }
        l0 = allred8(cvt2f(lc0));
        l1 = allred8(cvt2f(lc1));
      }

      float r00 = allred8(cvt2f(a00));
      float r01 = allred8(cvt2f(a01));
      float r10 = allred8(cvt2f(a10));
      float r11 = allred8(cvt2f(a11));

      // update right rows: lane ks=b owns batch b, rows j0,j0+1
      if (ks < 2) {
        float d0 = ks ? r10 : r00;
        float d1 = ks ? r11 : r01;
        float t0 = __uint_as_float(hbp[cur][ks][160]);
        float t1 = __uint_as_float(hbp[cur][ks][161]);
        float2 cv = *(const float2*)&cbuf[ks][s][2 * g];
        float pre0 = d0 + wt0.x * t0 + wt0.y * t1 + cv.x;
        float pre1 = d1 + wt1.x * t0 + wt1.y * t1 + cv.y;
        hc0 = 0.8f * hc0 + 0.2f * my_tanh(pre0);
        hc1 = 0.8f * hc1 + 0.2f * my_tanh(pre1);
        *(float2*)&sbuf[ks][s][2 * g] = make_float2(hc0, hc1);
        if (g == 127) {            // rows 256,257 -> f32 tail slots
          hbp[nxt][ks][160] = __float_as_uint(hc0);
          hbp[nxt][ks][161] = __float_as_uint(hc1);
        } else {
          hbp[nxt][ks][PK(g + 1)] = packh2(hc0, hc1);
        }
      }

      // left updaters: lane 0 (batch 0) and lane 8 (batch 1)
      if (tid < 16 && ks == 0) {
        const int lb = tid >> 3;
        float wl0t0 = __uint_as_float(wlp[0][160]);
        float wl0t1 = __uint_as_float(wlp[0][161]);
        float wl1t0 = __uint_as_float(wlp[1][160]);
        float wl1t1 = __uint_as_float(wlp[1][161]);
        float t0 = __uint_as_float(hbp[cur][lb][160]);
        float t1 = __uint_as_float(hbp[cur][lb][161]);
        float pre0 = l0 + wl0t0 * t0 + wl0t1 * t1 + cbuf[lb][s][256];
        float pre1 = l1 + wl1t0 * t0 + wl1t1 * t1 + cbuf[lb][s][257];
        hL0 = 0.8f * hL0 + 0.2f * my_tanh(pre0);
        hL1 = 0.8f * hL1 + 0.2f * my_tanh(pre1);
        hbp[nxt][lb][0] = packh2(hL0, hL1);   // PK(0) == 0 -> h[0],h[1]
        sbuf[lb][s][256] = hL0;
        sbuf[lb][s][257] = hL1;
      }

      step_barrier();
    }

    // flush sbuf -> hs (coalesced, both batch rows)
    const int fb = cc * 2064;
#pragma unroll
    for (int q = 0; q < 5; ++q) {
      int idx = tid + 1024 * q;
      if (idx < 4128) {
        int ro = idx >= 2064 ? 1 : 0;
        int ii = idx - 2064 * ro;
        int s = ii / 258, j = ii - 258 * s;
        int jj = (j < 2) ? (256 + j) : (j - 2);
        float vv = sbuf[ro][s][jj];
        if (ro) gO1[fb + ii] = vv; else gO0[fb + ii] = vv;
      }
    }

    // zs: wave w in [0,16) handles (row = w>>3, s = w&7)
    {
      int w = tid >> 6, lane = tid & 63;
      int ro = w >> 3, s = w & 7;
      float zacc = 0.f;
#pragma unroll
      for (int q = 0; q < 5; ++q) {
        int jj = lane + 64 * q;
        if (jj < 258) zacc = fmaf(sbuf[ro][s][jj], wrol[jj], zacc);
      }
#pragma unroll
      for (int m = 32; m >= 1; m >>= 1) zacc += __shfl_xor(zacc, m);
      if (lane == 0) gZ[ro * 400 + cc * 8 + s] = zacc + bro;
    }

    // generate next C chunk (pure VALU/LDS, no vmcnt dependency)
    if (cc < 49) gen_cbuf(cc + 1);
    step_barrier();
  }
}

// ---------------------------------------------------------------------------
extern "C" void kernel_launch(void* const* d_in, const int* in_sizes, int n_in,
                              void* d_out, int out_size, void* d_ws, size_t ws_size,
                              hipStream_t stream) {
  const float* xs   = (const float*)d_in[0];
  const float* w_ll = (const float*)d_in[1];
  const float* b_ll = (const float*)d_in[2];
  const float* w_rr = (const float*)d_in[3];
  const float* b_rr = (const float*)d_in[4];
  const float* w_lr = (const float*)d_in[5];
  const float* w_rl = (const float*)d_in[6];
  const float* w_xl = (const float*)d_in[7];
  const float* w_xr = (const float*)d_in[8];
  const float* w_ro = (const float*)d_in[9];
  const float* b_ro = (const float*)d_in[10];

  float* hs = (float*)d_out;                    // 512*400*258 (+ zs after)

  uint32_t* Wp  = (uint32_t*)d_ws;              // 258*128 = 33,024 u32
  float* Wtail  = (float*)(Wp + 33024);         // 516

  uint32_t nk[3][2];
  for (uint32_t i = 0; i < 3; ++i) {
    uint32_t o0, o1;
    tf2x32(0u, 42u, 0u, i, o0, o1);
    nk[i][0] = o0; nk[i][1] = o1;
  }

  build_w_kernel<<<129, 256, 0, stream>>>(w_ll, w_rl, w_lr, w_rr, Wp, Wtail);
  rnn_scan_kernel<<<256, 1024, 0, stream>>>(Wp, Wtail, hs, w_ro, b_ro, xs,
                                            w_xl, w_xr, b_ll, b_rr,
                                            nk[0][0], nk[0][1], nk[1][0], nk[1][1],
                                            nk[2][0], nk[2][1]);
}